// Round 2
// baseline (49.302 us; speedup 1.0000x reference)
//
#include <hip/hip_runtime.h>

#define IW 512
#define IH 512
#define NPLANES 24      // B*C = 8*3
#define NSTEPS 7
#define GROUPS 2        // plane-split factor: grid = 1024*GROUPS blocks
#define PPT (NPLANES / GROUPS)

__global__ __launch_bounds__(256) void zoomblur_kernel(
    const float* __restrict__ img,
    const float* __restrict__ zoomf,
    float* __restrict__ out)
{
    const int bid      = blockIdx.x;
    const int group    = bid & (GROUPS - 1);
    const int pixblock = bid >> 1;              // log2(GROUPS)
    const int pix = pixblock * blockDim.x + threadIdx.x;   // 0 .. 512*512-1
    const int x = pix & (IW - 1);
    const int y = pix >> 9;

    const float zf = 0.85f + 0.30f * zoomf[0];
    const float dz = zf - 1.0f;

    const float xf = (float)x - 256.0f;
    const float yf = (float)y - 256.0f;

    int   off[NSTEPS - 1];
    float w00[NSTEPS - 1], w01[NSTEPS - 1], w10[NSTEPS - 1], w11[NSTEPS - 1];

    // Interior test: coords are monotone in s, extreme at s=6 (scale=zf).
    // For dz>0 (inv<1) sources shrink toward center -> always interior and
    // the test passes naturally. For dz<0 the s=6 tap is the outermost.
    const float inv6 = 1.0f / (1.0f + dz);
    const float xs6f = xf * inv6 + 256.0f;
    const float ys6f = yf * inv6 + 256.0f;
    const int x06 = (int)floorf(xs6f);
    const int y06 = (int)floorf(ys6f);
    const bool interior = (x06 >= 0) & (x06 <= IW - 2) & (y06 >= 0) & (y06 <= IH - 2);

    if (interior) {
#pragma unroll
        for (int s = 1; s < NSTEPS; ++s) {
            const float scale = 1.0f + ((float)s * (1.0f / 6.0f)) * dz;
            const float inv   = 1.0f / scale;
            const float xs = xf * inv + 256.0f;
            const float ys = yf * inv + 256.0f;
            const float x0f = floorf(xs);
            const float y0f = floorf(ys);
            const float wx = xs - x0f;
            const float wy = ys - y0f;
            const int k = s - 1;
            off[k] = (int)y0f * IW + (int)x0f;
            const float s0 = 1.0f - wx, s1 = wx;
            const float t0 = 1.0f - wy, t1 = wy;
            w00[k] = s0 * t0;
            w01[k] = s1 * t0;
            w10[k] = s0 * t1;
            w11[k] = s1 * t1;
        }
    } else {
#pragma unroll
        for (int s = 1; s < NSTEPS; ++s) {
            const float scale = 1.0f + ((float)s * (1.0f / 6.0f)) * dz;
            const float inv   = 1.0f / scale;
            const float xs = xf * inv + 256.0f;
            const float ys = yf * inv + 256.0f;
            const float x0f = floorf(xs);
            const float y0f = floorf(ys);
            const float wx = xs - x0f;
            const float wy = ys - y0f;
            const int x0 = (int)x0f;
            const int y0 = (int)y0f;
            const int xb = min(max(x0, 0), IW - 2);
            const int yb = min(max(y0, 0), IH - 2);
            // remap tap weights onto slots (xb, xb+1), zeroing invalid taps
            float s0 = 0.0f, s1 = 0.0f;
            if (x0 == xb)          { s0 = 1.0f - wx; s1 = wx; }
            else if (x0 == xb - 1) { s0 = wx; }
            else if (x0 == xb + 1) { s1 = 1.0f - wx; }
            float t0 = 0.0f, t1 = 0.0f;
            if (y0 == yb)          { t0 = 1.0f - wy; t1 = wy; }
            else if (y0 == yb - 1) { t0 = wy; }
            else if (y0 == yb + 1) { t1 = 1.0f - wy; }
            const int k = s - 1;
            off[k] = yb * IW + xb;
            w00[k] = s0 * t0;
            w01[k] = s1 * t0;
            w10[k] = s0 * t1;
            w11[k] = s1 * t1;
        }
    }

    // plane loop over this group's 12 planes; offsets/weights reused
    const float* __restrict__ ibase = img + (size_t)(group * PPT) * (IH * IW);
    float* __restrict__       obase = out + (size_t)(group * PPT) * (IH * IW);
#pragma unroll 1
    for (int p = 0; p < PPT; ++p) {
        const float* __restrict__ base = ibase + (size_t)p * (IH * IW);
        float acc0 = base[pix];   // step 0: scale == 1 exactly -> identity
        float acc1 = 0.0f;
#pragma unroll
        for (int k = 0; k < NSTEPS - 1; ++k) {
            const float* r0 = base + off[k];
            const float* r1 = r0 + IW;
            const float p00 = r0[0];
            const float p01 = r0[1];
            const float p10 = r1[0];
            const float p11 = r1[1];
            // two accumulator chains to halve the serial FMA latency
            acc0 = fmaf(w00[k], p00, acc0);
            acc1 = fmaf(w01[k], p01, acc1);
            acc0 = fmaf(w10[k], p10, acc0);
            acc1 = fmaf(w11[k], p11, acc1);
        }
        obase[(size_t)p * (IH * IW) + pix] = (acc0 + acc1) * (1.0f / 7.0f);
    }
}

extern "C" void kernel_launch(void* const* d_in, const int* in_sizes, int n_in,
                              void* d_out, int out_size, void* d_ws, size_t ws_size,
                              hipStream_t stream) {
    const float* img  = (const float*)d_in[0];
    const float* zoom = (const float*)d_in[1];
    float* out = (float*)d_out;

    const int npix = IH * IW;               // 262144
    dim3 block(256);
    dim3 grid((npix / 256) * GROUPS);       // 2048 blocks -> 8 blocks/CU
    zoomblur_kernel<<<grid, block, 0, stream>>>(img, zoom, out);
}

// Round 3
// 36.114 us; speedup vs baseline: 1.3652x; 1.3652x over previous
//
#include <hip/hip_runtime.h>

#define IW 512
#define IH 512
#define NPLANES 24      // B*C
#define NSTEPS 7
#define NK (NSTEPS - 1)
#define GROUPS 2        // plane-split: 12 planes per thread
#define PPT (NPLANES / GROUPS)

// 4-byte-aligned vector types: gfx950 global loads only need dword alignment,
// backend still emits global_load_dwordx4 / dwordx2.
typedef float f4v __attribute__((ext_vector_type(4), aligned(4)));
typedef float f2v __attribute__((ext_vector_type(2), aligned(8)));

__global__ __launch_bounds__(256) void zoomblur_kernel(
    const float* __restrict__ img,
    const float* __restrict__ zoomf,
    float* __restrict__ out)
{
    const int bid   = blockIdx.x;
    const int group = bid & (GROUPS - 1);
    const int tix   = (bid >> 1) * blockDim.x + threadIdx.x; // pair index 0..131071
    const int xL  = (tix & (IW / 2 - 1)) * 2;                // even x of the pair
    const int y   = tix >> 8;                                // 256 pairs per row
    const int pix = y * IW + xL;

    const float zf = 0.85f + 0.30f * zoomf[0];
    const float dz = zf - 1.0f;

    const float xfL = (float)xL - 256.0f;
    const float xfR = xfL + 1.0f;
    const float yf  = (float)y - 256.0f;

    int   off[NK];
    float t0a[NK], t1a[NK];
    float wcL[NK][4], wcR[NK][4];

    // One-time per-thread precompute, reused across 12 planes.
    // Loads per step: one dwordx4 per source row at base bL; both pixels'
    // column taps land in slots [0,4) (proof: 1/scale <= 1.177 -> x0R <= x0L+2,
    // clamping bL to [0, IW-4] keeps every VALID column inside the window).
    // Zero-padding: a tap column/row contributes iff it matches a loaded
    // slot, expressed as branch-free predicates below.
#pragma unroll
    for (int s = 1; s < NSTEPS; ++s) {
        const int k = s - 1;
        const float scale = 1.0f + ((float)s * (1.0f / 6.0f)) * dz;
        const float inv   = 1.0f / scale;
        const float xsL = xfL * inv + 256.0f;
        const float xsR = xfR * inv + 256.0f;
        const float ys  = yf  * inv + 256.0f;
        const float fxL = floorf(xsL), fxR = floorf(xsR), fy = floorf(ys);
        const float wxL = xsL - fxL, wxR = xsR - fxR, wy = ys - fy;
        const int x0L = (int)fxL, x0R = (int)fxR, y0 = (int)fy;
        const int bL = min(max(x0L, 0), IW - 4);
        const int yb = min(max(y0, 0), IH - 2);
        off[k] = yb * IW + bL;
        // row weights mapped onto loaded rows {yb, yb+1}
        t0a[k] = (yb == y0 ? 1.0f - wy : 0.0f) + (yb == y0 + 1 ? wy : 0.0f);
        t1a[k] = (yb + 1 == y0 ? 1.0f - wy : 0.0f) + (yb + 1 == y0 + 1 ? wy : 0.0f);
        // column weights mapped onto slots bL..bL+3 (all statically indexed)
#pragma unroll
        for (int j = 0; j < 4; ++j) {
            const int c = bL + j;
            wcL[k][j] = (c == x0L ? 1.0f - wxL : 0.0f) + (c == x0L + 1 ? wxL : 0.0f);
            wcR[k][j] = (c == x0R ? 1.0f - wxR : 0.0f) + (c == x0R + 1 ? wxR : 0.0f);
        }
    }

    const float* __restrict__ ib = img + (size_t)(group * PPT) * (IH * IW);
    float* __restrict__       ob = out + (size_t)(group * PPT) * (IH * IW);
#pragma unroll 1
    for (int p = 0; p < PPT; ++p) {
        const float* __restrict__ base = ib + (size_t)p * (IH * IW);
        const f2v id = *(const f2v*)(base + pix);   // step 0: exact identity
        float aL = id.x;
        float aR = id.y;
#pragma unroll
        for (int k = 0; k < NK; ++k) {
            const float* rp = base + off[k];
            const f4v r0 = *(const f4v*)rp;          // row yb
            const f4v r1 = *(const f4v*)(rp + IW);   // row yb+1
            const float c0 = fmaf(t0a[k], r0.x, t1a[k] * r1.x);
            const float c1 = fmaf(t0a[k], r0.y, t1a[k] * r1.y);
            const float c2 = fmaf(t0a[k], r0.z, t1a[k] * r1.z);
            const float c3 = fmaf(t0a[k], r0.w, t1a[k] * r1.w);
            aL = fmaf(wcL[k][0], c0, fmaf(wcL[k][1], c1,
                 fmaf(wcL[k][2], c2, fmaf(wcL[k][3], c3, aL))));
            aR = fmaf(wcR[k][0], c0, fmaf(wcR[k][1], c1,
                 fmaf(wcR[k][2], c2, fmaf(wcR[k][3], c3, aR))));
        }
        f2v o;
        o.x = aL * (1.0f / 7.0f);
        o.y = aR * (1.0f / 7.0f);
        *(f2v*)(ob + (size_t)p * (IH * IW) + pix) = o;
    }
}

extern "C" void kernel_launch(void* const* d_in, const int* in_sizes, int n_in,
                              void* d_out, int out_size, void* d_ws, size_t ws_size,
                              hipStream_t stream) {
    const float* img  = (const float*)d_in[0];
    const float* zoom = (const float*)d_in[1];
    float* out = (float*)d_out;

    const int npairs = IH * IW / 2;                 // 131072
    dim3 block(256);
    dim3 grid((npairs / 256) * GROUPS);             // 1024 blocks
    zoomblur_kernel<<<grid, block, 0, stream>>>(img, zoom, out);
}

// Round 4
// 25.113 us; speedup vs baseline: 1.9632x; 1.4381x over previous
//
#include <hip/hip_runtime.h>

#define IW 512
#define IH 512
#define NPIX (IH * IW)
#define NPLANES 24      // B*C
#define NK 6            // steps 1..6 (step 0 is exact identity)
#define GROUPS 8        // plane-split: 3 planes per block
#define PPT (NPLANES / GROUPS)
#define LROW 520        // padded LDS row stride (floats); 520*4B = 16B-multiple

typedef float f4v __attribute__((ext_vector_type(4), aligned(4)));
typedef float f2v __attribute__((ext_vector_type(2), aligned(8)));

struct StageInfo { int rowA, rowB; float t0, t1; };

// Row-tap prep for step s (block-uniform: depends only on y,s).
__device__ inline StageInfo stage_prep(int s, float yf, float dz) {
    const float inv = 1.0f / (1.0f + (float)s * (1.0f / 6.0f) * dz);
    const float ysv = yf * inv + 256.0f;
    const float fy  = floorf(ysv);
    const float wy  = ysv - fy;
    const int y0 = (int)fy;
    const int yb = min(max(y0, 0), IH - 2);
    StageInfo si;
    // weights remapped onto loaded rows {yb, yb+1}; zero when tap row invalid
    si.t0 = (yb == y0 ? 1.0f - wy : 0.0f) + (yb == y0 + 1 ? wy : 0.0f);
    si.t1 = (yb + 1 == y0 ? 1.0f - wy : 0.0f) + (yb + 1 == y0 + 1 ? wy : 0.0f);
    si.rowA = yb * IW;
    si.rowB = si.rowA + IW;
    return si;
}

__global__ __launch_bounds__(256) void zoomblur_kernel(
    const float* __restrict__ img,
    const float* __restrict__ zoomf,
    float* __restrict__ out)
{
    __shared__ float rrow[NK * LROW];   // 12.2 KB: 6 row-interpolated lines

    const int tid   = threadIdx.x;
    const int bid   = blockIdx.x;
    const int group = bid & (GROUPS - 1);
    const int y     = bid >> 3;                 // one output row per block
    const int xL    = tid * 2;                  // thread owns pixels xL, xL+1

    const float zf = 0.85f + 0.30f * zoomf[0];
    const float dz = zf - 1.0f;
    const float yf  = (float)y - 256.0f;
    const float xfL = (float)xL - 256.0f;
    const float xfR = xfL + 1.0f;

    // ---- per-thread column taps for all 6 steps (static-indexed arrays) ----
    int   offL[NK], offR[NK];
    float wL0[NK], wL1[NK], wR0[NK], wR1[NK];
#pragma unroll
    for (int s = 1; s <= NK; ++s) {
        const int k = s - 1;
        const float inv = 1.0f / (1.0f + (float)s * (1.0f / 6.0f) * dz);
        const float xsL = xfL * inv + 256.0f;
        const float xsR = xfR * inv + 256.0f;
        const float fxL = floorf(xsL), fxR = floorf(xsR);
        const float wxL = xsL - fxL,  wxR = xsR - fxR;
        const int x0L = (int)fxL, x0R = (int)fxR;
        const int xcL = min(max(x0L, 0), IW - 2);
        const int xcR = min(max(x0R, 0), IW - 2);
        // slot-remapped weights: tap contributes iff its column matches a slot
        wL0[k] = (xcL == x0L ? 1.0f - wxL : 0.0f) + (xcL == x0L + 1 ? wxL : 0.0f);
        wL1[k] = (xcL + 1 == x0L ? 1.0f - wxL : 0.0f) + (xcL + 1 == x0L + 1 ? wxL : 0.0f);
        wR0[k] = (xcR == x0R ? 1.0f - wxR : 0.0f) + (xcR == x0R + 1 ? wxR : 0.0f);
        wR1[k] = (xcR + 1 == x0R ? 1.0f - wxR : 0.0f) + (xcR + 1 == x0R + 1 ? wxR : 0.0f);
        offL[k] = k * LROW + xcL;
        offR[k] = k * LROW + xcR;
    }

    // ---- staging role: this thread stages col-quad cq of steps s0,s1,s2 ----
    const int sbase = tid >> 7;             // 0 or 1
    const int cq    = (tid & 127) << 2;     // 0..508
    const StageInfo si0 = stage_prep(sbase + 1, yf, dz);
    const StageInfo si1 = stage_prep(sbase + 3, yf, dz);
    const StageInfo si2 = stage_prep(sbase + 5, yf, dz);
    float* w0 = &rrow[(sbase + 0) * LROW + cq];
    float* w1 = &rrow[(sbase + 2) * LROW + cq];
    float* w2 = &rrow[(sbase + 4) * LROW + cq];

    const int idoff = y * IW + xL;
    const size_t pbase = (size_t)(group * PPT) * NPIX;
    const float* __restrict__ ib = img + pbase;
    float* __restrict__       ob = out + pbase;

    // prologue: plane 0 staging loads
    const float* bp = ib;
    f4v a0 = *(const f4v*)(bp + si0.rowA + cq);
    f4v b0 = *(const f4v*)(bp + si0.rowB + cq);
    f4v a1 = *(const f4v*)(bp + si1.rowA + cq);
    f4v b1 = *(const f4v*)(bp + si1.rowB + cq);
    f4v a2 = *(const f4v*)(bp + si2.rowA + cq);
    f4v b2 = *(const f4v*)(bp + si2.rowB + cq);
    f2v idv = *(const f2v*)(bp + idoff);

#pragma unroll
    for (int p = 0; p < PPT; ++p) {
        // write row-interpolated lines for this plane
        *(f4v*)w0 = si0.t0 * a0 + si0.t1 * b0;
        *(f4v*)w1 = si1.t0 * a1 + si1.t1 * b1;
        *(f4v*)w2 = si2.t0 * a2 + si2.t1 * b2;
        __syncthreads();

        const float idx0 = idv.x, idx1 = idv.y;
        // prefetch next plane's rows while we compute from LDS
        if (p + 1 < PPT) {
            const float* np = ib + (size_t)(p + 1) * NPIX;
            a0 = *(const f4v*)(np + si0.rowA + cq);
            b0 = *(const f4v*)(np + si0.rowB + cq);
            a1 = *(const f4v*)(np + si1.rowA + cq);
            b1 = *(const f4v*)(np + si1.rowB + cq);
            a2 = *(const f4v*)(np + si2.rowA + cq);
            b2 = *(const f4v*)(np + si2.rowB + cq);
            idv = *(const f2v*)(np + idoff);
        }

        float aL = idx0, aR = idx1;
#pragma unroll
        for (int k = 0; k < NK; ++k) {
            const float v0L = rrow[offL[k]];
            const float v1L = rrow[offL[k] + 1];
            const float v0R = rrow[offR[k]];
            const float v1R = rrow[offR[k] + 1];
            aL = fmaf(wL0[k], v0L, fmaf(wL1[k], v1L, aL));
            aR = fmaf(wR0[k], v0R, fmaf(wR1[k], v1R, aR));
        }
        f2v o;
        o.x = aL * (1.0f / 7.0f);
        o.y = aR * (1.0f / 7.0f);
        *(f2v*)(ob + (size_t)p * NPIX + idoff) = o;
        __syncthreads();   // LDS reuse fence before next plane's writes
    }
}

extern "C" void kernel_launch(void* const* d_in, const int* in_sizes, int n_in,
                              void* d_out, int out_size, void* d_ws, size_t ws_size,
                              hipStream_t stream) {
    const float* img  = (const float*)d_in[0];
    const float* zoom = (const float*)d_in[1];
    float* out = (float*)d_out;

    dim3 block(256);
    dim3 grid(IH * GROUPS);      // 4096 blocks: (row y) x (plane group)
    zoomblur_kernel<<<grid, block, 0, stream>>>(img, zoom, out);
}